// Round 5
// baseline (706.871 us; speedup 1.0000x reference)
//
#include <hip/hip_runtime.h>
#include <hip/hip_fp16.h>
#include <math.h>

// Problem constants (from setup_inputs)
#define NN   50000          // nodes
#define EE   800000         // edges (without self loops)
#define ETOT 850000         // edges + self loops
#define INF_FEATS 22
#define D1   256            // HEADS*HID
#define NH   4
#define D2   32
#define BN_EPS 1e-5f
#define NEG_SLOPE 0.2f

__device__ __forceinline__ float wsum64(float v) {
#pragma unroll
    for (int m = 32; m > 0; m >>= 1) v += __shfl_xor(v, m);
    return v;
}

// ---------------------------------------------------------------------------
// sAB: h1 = x@W1 (block=node, thread=col) + fused attention dots per head
__global__ __launch_bounds__(256) void sAB(const float* __restrict__ x,
                                           const float* __restrict__ W1,
                                           const float* __restrict__ atts,
                                           const float* __restrict__ attd,
                                           float* __restrict__ h1,
                                           float* __restrict__ as1,
                                           float* __restrict__ ad1) {
    const int n = blockIdx.x, col = threadIdx.x;
    float a = 0.f;
#pragma unroll
    for (int k = 0; k < INF_FEATS; ++k)
        a = fmaf(x[n * INF_FEATS + k], W1[k * D1 + col], a);
    h1[n * D1 + col] = a;
    const int w = col >> 6, lane = col & 63;
    const float s = wsum64(a * atts[col]);
    const float d = wsum64(a * attd[col]);
    if (lane == 0) {
        as1[n * NH + w] = s;
        ad1[n * NH + w] = d;
    }
}

// ---------------------------------------------------------------------------
// CSR build
__global__ void c_count(const int* __restrict__ ei, int* __restrict__ cnt) {
    int e = blockIdx.x * blockDim.x + threadIdx.x;
    if (e >= ETOT) return;
    int dst = (e < EE) ? ei[EE + e] : (e - EE);
    atomicAdd(&cnt[dst], 1);
}

// 3-phase coalesced scan: 49 blocks x 1024
#define SCAN_B 49
__global__ __launch_bounds__(1024) void scan_a(const int* __restrict__ cnt,
                                               int* __restrict__ offs,
                                               int* __restrict__ bsum) {
    __shared__ int sh[1024];
    const int t = threadIdx.x, i = blockIdx.x * 1024 + t;
    const int v = (i < NN) ? cnt[i] : 0;
    sh[t] = v;
    __syncthreads();
    for (int off = 1; off < 1024; off <<= 1) {
        int u = (t >= off) ? sh[t - off] : 0;
        __syncthreads();
        sh[t] += u;
        __syncthreads();
    }
    if (i < NN) offs[i] = sh[t] - v;          // local exclusive
    if (t == 1023) bsum[blockIdx.x] = sh[1023];
}

__global__ void scan_b(const int* __restrict__ bsum, int* __restrict__ bbase,
                       int* __restrict__ offs) {
    if (threadIdx.x == 0) {
        int run = 0;
        for (int b = 0; b < SCAN_B; ++b) {
            bbase[b] = run;
            run += bsum[b];
        }
        offs[NN] = run;   // == ETOT
    }
}

__global__ __launch_bounds__(1024) void scan_c(int* __restrict__ offs,
                                               const int* __restrict__ bbase,
                                               int* __restrict__ cur) {
    const int i = blockIdx.x * 1024 + threadIdx.x;
    if (i >= NN) return;
    const int o = offs[i] + bbase[blockIdx.x];
    offs[i] = o;
    cur[i] = o;
}

// ---------------------------------------------------------------------------
// c_scatterA: scatter src into CSR order + per-edge per-head alpha numerators
// (fp16) + atomic per-(dst,head) denominators.
__global__ void c_scatterA(const int* __restrict__ ei,
                           const float* __restrict__ as1,
                           const float* __restrict__ ad1,
                           int* __restrict__ cur, int* __restrict__ ssrc,
                           __half* __restrict__ anum, float* __restrict__ s1) {
    int e = blockIdx.x * blockDim.x + threadIdx.x;
    if (e >= ETOT) return;
    int s, d;
    if (e < EE) { s = ei[e]; d = ei[EE + e]; }
    else        { s = d = e - EE; }
    int pos = atomicAdd(&cur[d], 1);
    ssrc[pos] = s;
#pragma unroll
    for (int h = 0; h < NH; ++h) {
        float a = as1[s * NH + h] + ad1[d * NH + h];
        a = (a >= 0.f) ? a : NEG_SLOPE * a;
        const float p = __expf(a);
        anum[pos * NH + h] = __float2half(p);
        atomicAdd(&s1[d * NH + h], p);
    }
}

// ---------------------------------------------------------------------------
// g1k: layer-1 gather. Block = dst node, thread = col, wave = head.
// Hot loop: ssrc + precomputed alpha numerator + h1-row fma only.
__global__ __launch_bounds__(256) void g1k(
    const float* __restrict__ h1, const __half* __restrict__ anum,
    const float* __restrict__ s1, const int* __restrict__ offs,
    const int* __restrict__ ssrc, const float* __restrict__ b1,
    const float* __restrict__ g1, const float* __restrict__ be1,
    const float* __restrict__ mu1, const float* __restrict__ va1,
    float* __restrict__ hpost) {
    const int n = blockIdx.x, col = threadIdx.x, w = col >> 6;
    const int off = offs[n];
    const int deg = offs[n + 1] - off;
    float acc = 0.f;
    for (int p = 0; p < deg; ++p) {
        const int sj = ssrc[off + p];                       // wave-uniform
        const float al = __half2float(anum[(off + p) * NH + w]);
        acc = fmaf(al, h1[sj * D1 + col], acc);
    }
    const float ssum = s1[n * NH + w];
    float v = acc / (ssum + 1e-16f) + b1[col];
    v = (v - mu1[col]) * rsqrtf(va1[col] + BN_EPS) * g1[col] + be1[col];
    v = (v > 0.f) ? v : expm1f(v);
    hpost[n * D1 + col] = v;
}

// ---------------------------------------------------------------------------
// sF: h2 = hpost @ W2; 8 nodes/block, W2 staged in LDS
__global__ __launch_bounds__(256) void sF(const float* __restrict__ hpost,
                                          const float* __restrict__ W2,
                                          float* __restrict__ h2) {
    __shared__ float w2s[D1 * D2];   // 32 KB
    const int t = threadIdx.x;
    for (int i = t; i < D1 * D2; i += 256) w2s[i] = W2[i];
    __syncthreads();
    const int n = blockIdx.x * 8 + (t >> 5), c = t & 31;
    float a = 0.f;
#pragma unroll 4
    for (int k = 0; k < D1; ++k)
        a = fmaf(hpost[n * D1 + k], w2s[k * D2 + c], a);
    h2[n * D2 + c] = a;
}

// sG: attention dots layer 2, thread per n
__global__ void sG(const float* __restrict__ h2, const float* __restrict__ atts,
                   const float* __restrict__ attd, float* __restrict__ as2,
                   float* __restrict__ ad2) {
    const int n = blockIdx.x * 256 + threadIdx.x;
    if (n >= NN) return;
    float s = 0.f, d = 0.f;
    for (int c = 0; c < D2; ++c) {
        const float v = h2[n * D2 + c];
        s = fmaf(v, atts[c], s);
        d = fmaf(v, attd[c], d);
    }
    as2[n] = s;
    ad2[n] = d;
}

// ---------------------------------------------------------------------------
// g2k: layer-2 gather. 8 nodes/block, 32 lanes per node (trusted Round-4 code).
__global__ __launch_bounds__(256) void g2k(
    const float* __restrict__ h2, const float* __restrict__ as2,
    const float* __restrict__ ad2, const int* __restrict__ offs,
    const int* __restrict__ ssrc, const float* __restrict__ b2,
    const float* __restrict__ g2, const float* __restrict__ be2,
    const float* __restrict__ mu2, const float* __restrict__ va2,
    float* __restrict__ out) {
    const int t = threadIdx.x;
    const int n = blockIdx.x * 8 + (t >> 5), c = t & 31;
    const int off = offs[n];
    const int deg = offs[n + 1] - off;
    const float adst = ad2[n];
    float ssum = 0.f, acc = 0.f;
    for (int p = 0; p < deg; ++p) {
        const int sj = ssrc[off + p];
        float a = as2[sj] + adst;
        a = (a >= 0.f) ? a : NEG_SLOPE * a;
        const float al = __expf(a);
        ssum += al;
        acc = fmaf(al, h2[sj * D2 + c], acc);
    }
    float v = acc / (ssum + 1e-16f) + b2[c];
    v = (v - mu2[c]) * rsqrtf(va2[c] + BN_EPS) * g2[c] + be2[c];
    v = (v > 0.f) ? v : expm1f(v);
    out[n * D2 + c] = v;
}

// ---------------------------------------------------------------------------
extern "C" void kernel_launch(void* const* d_in, const int* in_sizes, int n_in,
                              void* d_out, int out_size, void* d_ws, size_t ws_size,
                              hipStream_t stream) {
    (void)in_sizes; (void)n_in; (void)out_size; (void)ws_size;
    const float* x    = (const float*)d_in[0];
    const int*   ei   = (const int*)  d_in[1];
    const float* W1   = (const float*)d_in[2];
    const float* as1i = (const float*)d_in[3];
    const float* ad1i = (const float*)d_in[4];
    const float* b1   = (const float*)d_in[5];
    const float* W2   = (const float*)d_in[6];
    const float* as2i = (const float*)d_in[7];
    const float* ad2i = (const float*)d_in[8];
    const float* b2   = (const float*)d_in[9];
    const float* g1   = (const float*)d_in[10];
    const float* be1  = (const float*)d_in[11];
    const float* mu1  = (const float*)d_in[12];
    const float* va1  = (const float*)d_in[13];
    const float* g2   = (const float*)d_in[14];
    const float* be2  = (const float*)d_in[15];
    const float* mu2  = (const float*)d_in[16];
    const float* va2  = (const float*)d_in[17];
    float* out = (float*)d_out;

    // workspace layout (~117.3 MB, under the 118.4 MB proven in Round 3)
    float* ws = (float*)d_ws;
    float* h1    = ws;                          // NN*256 = 12.8M f
    float* hpost = h1 + (size_t)NN * D1;        // NN*256 = 12.8M f
    float* as1   = hpost + (size_t)NN * D1;     // NN*4
    float* ad1   = as1 + (size_t)NN * NH;       // NN*4
    float* s1    = ad1 + (size_t)NN * NH;       // NN*4
    float* as2   = s1 + (size_t)NN * NH;        // NN
    float* ad2   = as2 + NN;                    // NN
    float* h2    = ad2 + NN;                    // NN*32 = 1.6M f
    __half* anum = (__half*)(h2 + (size_t)NN * D2);  // ETOT*4 halves = 1.7MB
    int* cnt   = (int*)(anum + (size_t)ETOT * NH);   // NN
    int* offs  = cnt + NN;                      // NN+1
    int* cur   = offs + NN + 1;                 // NN
    int* ssrc  = cur + NN;                      // ETOT
    int* bsum  = ssrc + ETOT;                   // 49
    int* bbase = bsum + SCAN_B;                 // 49

    hipMemsetAsync(cnt, 0, NN * sizeof(int), stream);
    hipMemsetAsync(s1, 0, (size_t)NN * NH * sizeof(float), stream);

    // h1 + attention dots (fused)
    sAB<<<NN, 256, 0, stream>>>(x, W1, as1i, ad1i, h1, as1, ad1);
    // CSR build + per-edge alpha numerators/denominators
    c_count<<<(ETOT + 255) / 256, 256, 0, stream>>>(ei, cnt);
    scan_a<<<SCAN_B, 1024, 0, stream>>>(cnt, offs, bsum);
    scan_b<<<1, 64, 0, stream>>>(bsum, bbase, offs);
    scan_c<<<SCAN_B, 1024, 0, stream>>>(offs, bbase, cur);
    c_scatterA<<<(ETOT + 255) / 256, 256, 0, stream>>>(ei, as1, ad1, cur,
                                                       ssrc, anum, s1);
    // layer-1 gather (aggregate + BN + ELU)
    g1k<<<NN, 256, 0, stream>>>(h1, anum, s1, offs, ssrc,
                                b1, g1, be1, mu1, va1, hpost);
    // layer 2
    sF<<<NN / 8, 256, 0, stream>>>(hpost, W2, h2);
    sG<<<(NN + 255) / 256, 256, 0, stream>>>(h2, as2i, ad2i, as2, ad2);
    g2k<<<NN / 8, 256, 0, stream>>>(h2, as2, ad2, offs, ssrc,
                                    b2, g2, be2, mu2, va2, out);
}

// Round 6
// 543.151 us; speedup vs baseline: 1.3014x; 1.3014x over previous
//
#include <hip/hip_runtime.h>
#include <hip/hip_fp16.h>
#include <math.h>

// Problem constants (from setup_inputs)
#define NN   50000          // nodes
#define EE   800000         // edges (without self loops)
#define ETOT 850000         // edges + self loops
#define INF_FEATS 22
#define D1   256            // HEADS*HID
#define NH   4
#define D2   32
#define BN_EPS 1e-5f
#define NEG_SLOPE 0.2f
#define SCAN_B 49

__device__ __forceinline__ float wsum64(float v) {
#pragma unroll
    for (int m = 32; m > 0; m >>= 1) v += __shfl_xor(v, m);
    return v;
}

// ---------------------------------------------------------------------------
// sAB: h1 = x@W1 (block=node, thread=col), stored fp16; fused attention dots.
__global__ __launch_bounds__(256) void sAB(const float* __restrict__ x,
                                           const float* __restrict__ W1,
                                           const float* __restrict__ atts,
                                           const float* __restrict__ attd,
                                           __half* __restrict__ h1h,
                                           float* __restrict__ as1,
                                           float* __restrict__ ad1) {
    const int n = blockIdx.x, col = threadIdx.x;
    float a = 0.f;
#pragma unroll
    for (int k = 0; k < INF_FEATS; ++k)
        a = fmaf(x[n * INF_FEATS + k], W1[k * D1 + col], a);
    h1h[n * D1 + col] = __float2half(a);
    const int w = col >> 6, lane = col & 63;
    const float s = wsum64(a * atts[col]);
    const float d = wsum64(a * attd[col]);
    if (lane == 0) {
        as1[n * NH + w] = s;
        ad1[n * NH + w] = d;
    }
}

// ---------------------------------------------------------------------------
// CSR build: count / 3-phase scan / scatter
__global__ void c_count(const int* __restrict__ ei, int* __restrict__ cnt) {
    int e = blockIdx.x * blockDim.x + threadIdx.x;
    if (e >= ETOT) return;
    int dst = (e < EE) ? ei[EE + e] : (e - EE);
    atomicAdd(&cnt[dst], 1);
}

__global__ __launch_bounds__(1024) void scan_a(const int* __restrict__ cnt,
                                               int* __restrict__ offs,
                                               int* __restrict__ bsum) {
    __shared__ int sh[1024];
    const int t = threadIdx.x, i = blockIdx.x * 1024 + t;
    const int v = (i < NN) ? cnt[i] : 0;
    sh[t] = v;
    __syncthreads();
    for (int off = 1; off < 1024; off <<= 1) {
        int u = (t >= off) ? sh[t - off] : 0;
        __syncthreads();
        sh[t] += u;
        __syncthreads();
    }
    if (i < NN) offs[i] = sh[t] - v;          // local exclusive
    if (t == 1023) bsum[blockIdx.x] = sh[1023];
}

__global__ void scan_b(const int* __restrict__ bsum, int* __restrict__ bbase,
                       int* __restrict__ offs) {
    if (threadIdx.x == 0) {
        int run = 0;
        for (int b = 0; b < SCAN_B; ++b) {
            bbase[b] = run;
            run += bsum[b];
        }
        offs[NN] = run;   // == ETOT
    }
}

__global__ __launch_bounds__(1024) void scan_c(int* __restrict__ offs,
                                               const int* __restrict__ bbase,
                                               int* __restrict__ cur) {
    const int i = blockIdx.x * 1024 + threadIdx.x;
    if (i >= NN) return;
    const int o = offs[i] + bbase[blockIdx.x];
    offs[i] = o;
    cur[i] = o;
}

__global__ void c_scatter(const int* __restrict__ ei, int* __restrict__ cur,
                          int* __restrict__ ssrc) {
    int e = blockIdx.x * blockDim.x + threadIdx.x;
    if (e >= ETOT) return;
    int src, dst;
    if (e < EE) { src = ei[e]; dst = ei[EE + e]; }
    else        { src = dst = e - EE; }
    int pos = atomicAdd(&cur[dst], 1);
    ssrc[pos] = src;
}

// ---------------------------------------------------------------------------
// g1k: layer-1 gather. 2 nodes/block, 128 threads/node, thread = half2 col
// pair. alpha inline (|logit| small, exp safe — proven round 4). Fused BN+ELU.
__global__ __launch_bounds__(256) void g1k(
    const __half2* __restrict__ h1h2, const float* __restrict__ as1,
    const float* __restrict__ ad1, const int* __restrict__ offs,
    const int* __restrict__ ssrc, const float* __restrict__ b1,
    const float* __restrict__ g1, const float* __restrict__ be1,
    const float* __restrict__ mu1, const float* __restrict__ va1,
    float* __restrict__ hpost) {
    const int t = threadIdx.x;
    const int n = blockIdx.x * 2 + (t >> 7);   // grid exact: 25000*2
    const int tid = t & 127;                   // half2 index within row
    const int w = tid >> 5;                    // head = (2*tid)>>6
    const int off = offs[n];
    const int deg = offs[n + 1] - off;
    const float adst = ad1[n * NH + w];
    float ax = 0.f, ay = 0.f, ssum = 0.f;
    for (int p = 0; p < deg; ++p) {
        const int sj = ssrc[off + p];          // wave-uniform
        float a = as1[sj * NH + w] + adst;
        a = (a >= 0.f) ? a : NEG_SLOPE * a;
        const float al = __expf(a);
        ssum += al;
        const float2 f = __half22float2(h1h2[sj * (D1 / 2) + tid]);
        ax = fmaf(al, f.x, ax);
        ay = fmaf(al, f.y, ay);
    }
    const float inv = 1.f / (ssum + 1e-16f);
    const int c0 = tid * 2;
    float v0 = ax * inv + b1[c0];
    v0 = (v0 - mu1[c0]) * rsqrtf(va1[c0] + BN_EPS) * g1[c0] + be1[c0];
    v0 = (v0 > 0.f) ? v0 : expm1f(v0);
    float v1 = ay * inv + b1[c0 + 1];
    v1 = (v1 - mu1[c0 + 1]) * rsqrtf(va1[c0 + 1] + BN_EPS) * g1[c0 + 1] + be1[c0 + 1];
    v1 = (v1 > 0.f) ? v1 : expm1f(v1);
    hpost[n * D1 + c0]     = v0;
    hpost[n * D1 + c0 + 1] = v1;
}

// ---------------------------------------------------------------------------
// sFG: h2 = hpost @ W2 (fp16 out) + fused layer-2 attention dots.
// 8 nodes/block, 32 lanes per node, W2 staged in LDS.
__global__ __launch_bounds__(256) void sFG(const float* __restrict__ hpost,
                                           const float* __restrict__ W2,
                                           const float* __restrict__ atts,
                                           const float* __restrict__ attd,
                                           __half* __restrict__ h2h,
                                           float* __restrict__ as2,
                                           float* __restrict__ ad2) {
    __shared__ float w2s[D1 * D2];   // 32 KB
    const int t = threadIdx.x;
    for (int i = t; i < D1 * D2; i += 256) w2s[i] = W2[i];
    __syncthreads();
    const int n = blockIdx.x * 8 + (t >> 5), c = t & 31;  // grid exact: 6250*8
    float a = 0.f;
#pragma unroll 4
    for (int k = 0; k < D1; ++k)
        a = fmaf(hpost[n * D1 + k], w2s[k * D2 + c], a);
    h2h[n * D2 + c] = __float2half(a);
    float s = a * atts[c], d = a * attd[c];
#pragma unroll
    for (int m = 16; m > 0; m >>= 1) {   // xor <=16 stays within the 32-group
        s += __shfl_xor(s, m);
        d += __shfl_xor(d, m);
    }
    if (c == 0) { as2[n] = s; ad2[n] = d; }
}

// ---------------------------------------------------------------------------
// g2k: layer-2 gather (fp16 h2). 8 nodes/block, 32 lanes per node.
__global__ __launch_bounds__(256) void g2k(
    const __half* __restrict__ h2h, const float* __restrict__ as2,
    const float* __restrict__ ad2, const int* __restrict__ offs,
    const int* __restrict__ ssrc, const float* __restrict__ b2,
    const float* __restrict__ g2, const float* __restrict__ be2,
    const float* __restrict__ mu2, const float* __restrict__ va2,
    float* __restrict__ out) {
    const int t = threadIdx.x;
    const int n = blockIdx.x * 8 + (t >> 5), c = t & 31;
    const int off = offs[n];
    const int deg = offs[n + 1] - off;
    const float adst = ad2[n];
    float ssum = 0.f, acc = 0.f;
    for (int p = 0; p < deg; ++p) {
        const int sj = ssrc[off + p];
        float a = as2[sj] + adst;
        a = (a >= 0.f) ? a : NEG_SLOPE * a;
        const float al = __expf(a);
        ssum += al;
        acc = fmaf(al, __half2float(h2h[sj * D2 + c]), acc);
    }
    float v = acc / (ssum + 1e-16f) + b2[c];
    v = (v - mu2[c]) * rsqrtf(va2[c] + BN_EPS) * g2[c] + be2[c];
    v = (v > 0.f) ? v : expm1f(v);
    out[n * D2 + c] = v;
}

// ---------------------------------------------------------------------------
extern "C" void kernel_launch(void* const* d_in, const int* in_sizes, int n_in,
                              void* d_out, int out_size, void* d_ws, size_t ws_size,
                              hipStream_t stream) {
    (void)in_sizes; (void)n_in; (void)out_size; (void)ws_size;
    const float* x    = (const float*)d_in[0];
    const int*   ei   = (const int*)  d_in[1];
    const float* W1   = (const float*)d_in[2];
    const float* as1i = (const float*)d_in[3];
    const float* ad1i = (const float*)d_in[4];
    const float* b1   = (const float*)d_in[5];
    const float* W2   = (const float*)d_in[6];
    const float* as2i = (const float*)d_in[7];
    const float* ad2i = (const float*)d_in[8];
    const float* b2   = (const float*)d_in[9];
    const float* g1   = (const float*)d_in[10];
    const float* be1  = (const float*)d_in[11];
    const float* mu1  = (const float*)d_in[12];
    const float* va1  = (const float*)d_in[13];
    const float* g2   = (const float*)d_in[14];
    const float* be2  = (const float*)d_in[15];
    const float* mu2  = (const float*)d_in[16];
    const float* va2  = (const float*)d_in[17];
    float* out = (float*)d_out;

    // workspace layout (~86 MB, well under the 118.4 MB proven in Round 3)
    float* ws = (float*)d_ws;
    float* hpost = ws;                          // NN*256 f32
    float* as1   = hpost + (size_t)NN * D1;     // NN*4
    float* ad1   = as1 + (size_t)NN * NH;       // NN*4
    float* as2   = ad1 + (size_t)NN * NH;       // NN
    float* ad2   = as2 + NN;                    // NN
    __half* h1h  = (__half*)(ad2 + NN);         // NN*256 halves (25.6 MB)
    __half* h2h  = h1h + (size_t)NN * D1;       // NN*32 halves (3.2 MB)
    int* cnt   = (int*)(h2h + (size_t)NN * D2); // NN
    int* offs  = cnt + NN;                      // NN+1
    int* cur   = offs + NN + 1;                 // NN
    int* ssrc  = cur + NN;                      // ETOT
    int* bsum  = ssrc + ETOT;                   // 49
    int* bbase = bsum + SCAN_B;                 // 49

    hipMemsetAsync(cnt, 0, NN * sizeof(int), stream);

    // h1 (fp16) + attention dots (fused)
    sAB<<<NN, 256, 0, stream>>>(x, W1, as1i, ad1i, h1h, as1, ad1);
    // CSR build
    c_count<<<(ETOT + 255) / 256, 256, 0, stream>>>(ei, cnt);
    scan_a<<<SCAN_B, 1024, 0, stream>>>(cnt, offs, bsum);
    scan_b<<<1, 64, 0, stream>>>(bsum, bbase, offs);
    scan_c<<<SCAN_B, 1024, 0, stream>>>(offs, bbase, cur);
    c_scatter<<<(ETOT + 255) / 256, 256, 0, stream>>>(ei, cur, ssrc);
    // layer-1 gather (softmax + aggregate + BN + ELU)
    g1k<<<NN / 2, 256, 0, stream>>>((const __half2*)h1h, as1, ad1, offs, ssrc,
                                    b1, g1, be1, mu1, va1, hpost);
    // layer 2
    sFG<<<NN / 8, 256, 0, stream>>>(hpost, W2, as2i, ad2i, h2h, as2, ad2);
    g2k<<<NN / 8, 256, 0, stream>>>(h2h, as2, ad2, offs, ssrc,
                                    b2, g2, be2, mu2, va2, out);
}

// Round 8
// 420.575 us; speedup vs baseline: 1.6807x; 1.2914x over previous
//
#include <hip/hip_runtime.h>
#include <hip/hip_fp16.h>
#include <math.h>

// Problem constants (from setup_inputs)
#define NN   50000          // nodes
#define EE   800000         // edges (without self loops)
#define ETOT 850000         // edges + self loops
#define INF_FEATS 22
#define D1   256            // HEADS*HID
#define NH   4
#define D2   32
#define BN_EPS 1e-5f
#define NEG_SLOPE 0.2f
#define SCAN_B 49
#define CNT_BLOCKS ((ETOT + 255) / 256)

__device__ __forceinline__ float wsum64(float v) {
#pragma unroll
    for (int m = 32; m > 0; m >>= 1) v += __shfl_xor(v, m);
    return v;
}

__device__ __forceinline__ float2 h2f(unsigned u) {
    __half2 h = *reinterpret_cast<__half2*>(&u);
    return __half22float2(h);
}

// ---------------------------------------------------------------------------
// sAB_count: blocks [0,NN): h1 = x@W1 (fp16) + fused attention dots.
//            blocks [NN, NN+CNT_BLOCKS): edge-parallel degree count.
__global__ __launch_bounds__(256) void sAB_count(
    const float* __restrict__ x, const float* __restrict__ W1,
    const float* __restrict__ atts, const float* __restrict__ attd,
    const int* __restrict__ ei, __half* __restrict__ h1h,
    float* __restrict__ as1, float* __restrict__ ad1, int* __restrict__ cnt) {
    if (blockIdx.x >= NN) {
        const int e = (blockIdx.x - NN) * 256 + threadIdx.x;
        if (e < ETOT) {
            int dst = (e < EE) ? ei[EE + e] : (e - EE);
            atomicAdd(&cnt[dst], 1);
        }
        return;
    }
    const int n = blockIdx.x, col = threadIdx.x;
    float a = 0.f;
#pragma unroll
    for (int k = 0; k < INF_FEATS; ++k)
        a = fmaf(x[n * INF_FEATS + k], W1[k * D1 + col], a);
    h1h[n * D1 + col] = __float2half(a);
    const int w = col >> 6, lane = col & 63;
    const float s = wsum64(a * atts[col]);
    const float d = wsum64(a * attd[col]);
    if (lane == 0) {
        as1[n * NH + w] = s;
        ad1[n * NH + w] = d;
    }
}

// ---------------------------------------------------------------------------
// scan_a: per-block local exclusive scan of cnt
__global__ __launch_bounds__(1024) void scan_a(const int* __restrict__ cnt,
                                               int* __restrict__ offs,
                                               int* __restrict__ bsum) {
    __shared__ int sh[1024];
    const int t = threadIdx.x, i = blockIdx.x * 1024 + t;
    const int v = (i < NN) ? cnt[i] : 0;
    sh[t] = v;
    __syncthreads();
    for (int off = 1; off < 1024; off <<= 1) {
        int u = (t >= off) ? sh[t - off] : 0;
        __syncthreads();
        sh[t] += u;
        __syncthreads();
    }
    if (i < NN) offs[i] = sh[t] - v;          // local exclusive
    if (t == 1023) bsum[blockIdx.x] = sh[1023];
}

// scan_c: add block base (computed in-block from bsum), emit offs + cur
__global__ __launch_bounds__(1024) void scan_c(int* __restrict__ offs,
                                               const int* __restrict__ bsum,
                                               int* __restrict__ cur) {
    __shared__ int sbase;
    if (threadIdx.x == 0) {
        int r = 0;
        for (int b = 0; b < blockIdx.x; ++b) r += bsum[b];
        sbase = r;
    }
    __syncthreads();
    const int i = blockIdx.x * 1024 + threadIdx.x;
    if (i < NN) {
        const int o = offs[i] + sbase;
        offs[i] = o;
        cur[i] = o;
    }
    if (i == 0) offs[NN] = ETOT;
}

__global__ void c_scatter(const int* __restrict__ ei, int* __restrict__ cur,
                          int* __restrict__ ssrc) {
    int e = blockIdx.x * blockDim.x + threadIdx.x;
    if (e >= ETOT) return;
    int src, dst;
    if (e < EE) { src = ei[e]; dst = ei[EE + e]; }
    else        { src = dst = e - EE; }
    int pos = atomicAdd(&cur[dst], 1);
    ssrc[pos] = src;
}

// ---------------------------------------------------------------------------
// g1k: layer-1 gather. One wave per node (4 nodes/block). Lane = 4 channels
// (uint2 = half4 load). Unroll x8 with predication for 8 gathers in flight.
__global__ __launch_bounds__(256) void g1k(
    const uint2* __restrict__ h1q, const float* __restrict__ as1,
    const float* __restrict__ ad1, const int* __restrict__ offs,
    const int* __restrict__ ssrc, const float* __restrict__ b1,
    const float* __restrict__ g1, const float* __restrict__ be1,
    const float* __restrict__ mu1, const float* __restrict__ va1,
    float4* __restrict__ hpost) {
    const int wv = threadIdx.x >> 6, lane = threadIdx.x & 63;
    const int n = blockIdx.x * 4 + wv;       // grid exact: 12500*4
    const int off = offs[n];
    const int deg = offs[n + 1] - off;       // >= 1 (self loop)
    const int h = lane >> 4;                 // head = (lane*4)>>6
    const float adst = ad1[n * NH + h];
    float a0 = 0.f, a1 = 0.f, a2 = 0.f, a3 = 0.f, ssum = 0.f;
    for (int p = 0; p < deg; p += 8) {
        int sj[8];
        float al[8];
#pragma unroll
        for (int u = 0; u < 8; ++u)
            sj[u] = (p + u < deg) ? ssrc[off + p + u] : ssrc[off];
#pragma unroll
        for (int u = 0; u < 8; ++u) {
            float a = as1[sj[u] * NH + h] + adst;
            a = (a >= 0.f) ? a : NEG_SLOPE * a;
            al[u] = (p + u < deg) ? __expf(a) : 0.f;
        }
        uint2 hv[8];
#pragma unroll
        for (int u = 0; u < 8; ++u)
            hv[u] = h1q[(size_t)sj[u] * 64 + lane];
#pragma unroll
        for (int u = 0; u < 8; ++u) {
            ssum += al[u];
            const float2 f0 = h2f(hv[u].x), f1 = h2f(hv[u].y);
            a0 = fmaf(al[u], f0.x, a0);
            a1 = fmaf(al[u], f0.y, a1);
            a2 = fmaf(al[u], f1.x, a2);
            a3 = fmaf(al[u], f1.y, a3);
        }
    }
    const float inv = 1.f / (ssum + 1e-16f);
    const float4 bb = ((const float4*)b1)[lane];
    const float4 mm = ((const float4*)mu1)[lane];
    const float4 vv = ((const float4*)va1)[lane];
    const float4 gg = ((const float4*)g1)[lane];
    const float4 ee = ((const float4*)be1)[lane];
    float4 o;
    o.x = (a0 * inv + bb.x - mm.x) * rsqrtf(vv.x + BN_EPS) * gg.x + ee.x;
    o.y = (a1 * inv + bb.y - mm.y) * rsqrtf(vv.y + BN_EPS) * gg.y + ee.y;
    o.z = (a2 * inv + bb.z - mm.z) * rsqrtf(vv.z + BN_EPS) * gg.z + ee.z;
    o.w = (a3 * inv + bb.w - mm.w) * rsqrtf(vv.w + BN_EPS) * gg.w + ee.w;
    o.x = (o.x > 0.f) ? o.x : expm1f(o.x);
    o.y = (o.y > 0.f) ? o.y : expm1f(o.y);
    o.z = (o.z > 0.f) ? o.z : expm1f(o.z);
    o.w = (o.w > 0.f) ? o.w : expm1f(o.w);
    hpost[(size_t)n * 64 + lane] = o;
}

// ---------------------------------------------------------------------------
// sFG: h2 = hpost @ W2 (fp16 out) + fused layer-2 attention dots.
__global__ __launch_bounds__(256) void sFG(const float* __restrict__ hpost,
                                           const float* __restrict__ W2,
                                           const float* __restrict__ atts,
                                           const float* __restrict__ attd,
                                           __half* __restrict__ h2h,
                                           float* __restrict__ as2,
                                           float* __restrict__ ad2) {
    __shared__ float w2s[D1 * D2];   // 32 KB
    const int t = threadIdx.x;
    for (int i = t; i < D1 * D2; i += 256) w2s[i] = W2[i];
    __syncthreads();
    const int n = blockIdx.x * 8 + (t >> 5), c = t & 31;  // grid exact: 6250*8
    float a = 0.f;
#pragma unroll 4
    for (int k = 0; k < D1; ++k)
        a = fmaf(hpost[n * D1 + k], w2s[k * D2 + c], a);
    h2h[n * D2 + c] = __float2half(a);
    float s = a * atts[c], d = a * attd[c];
#pragma unroll
    for (int m = 16; m > 0; m >>= 1) {
        s += __shfl_xor(s, m);
        d += __shfl_xor(d, m);
    }
    if (c == 0) { as2[n] = s; ad2[n] = d; }
}

// ---------------------------------------------------------------------------
// g2k: layer-2 gather (fp16 h2, L2-resident). 8 nodes/block, unroll x8.
__global__ __launch_bounds__(256) void g2k(
    const unsigned short* __restrict__ h2u, const float* __restrict__ as2,
    const float* __restrict__ ad2, const int* __restrict__ offs,
    const int* __restrict__ ssrc, const float* __restrict__ b2,
    const float* __restrict__ g2, const float* __restrict__ be2,
    const float* __restrict__ mu2, const float* __restrict__ va2,
    float* __restrict__ out) {
    const int t = threadIdx.x;
    const int n = blockIdx.x * 8 + (t >> 5), c = t & 31;
    const int off = offs[n];
    const int deg = offs[n + 1] - off;
    const float adst = ad2[n];
    float ssum = 0.f, acc = 0.f;
    for (int p = 0; p < deg; p += 8) {
        int sj[8];
        float al[8];
#pragma unroll
        for (int u = 0; u < 8; ++u)
            sj[u] = (p + u < deg) ? ssrc[off + p + u] : ssrc[off];
#pragma unroll
        for (int u = 0; u < 8; ++u) {
            float a = as2[sj[u]] + adst;
            a = (a >= 0.f) ? a : NEG_SLOPE * a;
            al[u] = (p + u < deg) ? __expf(a) : 0.f;
        }
        unsigned short hv[8];
#pragma unroll
        for (int u = 0; u < 8; ++u)
            hv[u] = h2u[sj[u] * D2 + c];
#pragma unroll
        for (int u = 0; u < 8; ++u) {
            ssum += al[u];
            acc = fmaf(al[u], __half2float(*reinterpret_cast<__half*>(&hv[u])), acc);
        }
    }
    float v = acc / (ssum + 1e-16f) + b2[c];
    v = (v - mu2[c]) * rsqrtf(va2[c] + BN_EPS) * g2[c] + be2[c];
    v = (v > 0.f) ? v : expm1f(v);
    out[n * D2 + c] = v;
}

// ---------------------------------------------------------------------------
extern "C" void kernel_launch(void* const* d_in, const int* in_sizes, int n_in,
                              void* d_out, int out_size, void* d_ws, size_t ws_size,
                              hipStream_t stream) {
    (void)in_sizes; (void)n_in; (void)out_size; (void)ws_size;
    const float* x    = (const float*)d_in[0];
    const int*   ei   = (const int*)  d_in[1];
    const float* W1   = (const float*)d_in[2];
    const float* as1i = (const float*)d_in[3];
    const float* ad1i = (const float*)d_in[4];
    const float* b1   = (const float*)d_in[5];
    const float* W2   = (const float*)d_in[6];
    const float* as2i = (const float*)d_in[7];
    const float* ad2i = (const float*)d_in[8];
    const float* b2   = (const float*)d_in[9];
    const float* g1   = (const float*)d_in[10];
    const float* be1  = (const float*)d_in[11];
    const float* mu1  = (const float*)d_in[12];
    const float* va1  = (const float*)d_in[13];
    const float* g2   = (const float*)d_in[14];
    const float* be2  = (const float*)d_in[15];
    const float* mu2  = (const float*)d_in[16];
    const float* va2  = (const float*)d_in[17];
    float* out = (float*)d_out;

    // workspace layout (~86 MB, under the 118.4 MB proven in Round 3)
    float* ws = (float*)d_ws;
    float* hpost = ws;                          // NN*256 f32
    float* as1   = hpost + (size_t)NN * D1;     // NN*4
    float* ad1   = as1 + (size_t)NN * NH;       // NN*4
    float* as2   = ad1 + (size_t)NN * NH;       // NN
    float* ad2   = as2 + NN;                    // NN
    __half* h1h  = (__half*)(ad2 + NN);         // NN*256 halves (25.6 MB)
    __half* h2h  = h1h + (size_t)NN * D1;       // NN*32 halves (3.2 MB)
    int* cnt   = (int*)(h2h + (size_t)NN * D2); // NN
    int* offs  = cnt + NN;                      // NN+1
    int* cur   = offs + NN + 1;                 // NN
    int* ssrc  = cur + NN;                      // ETOT
    int* bsum  = ssrc + ETOT;                   // 49

    hipMemsetAsync(cnt, 0, NN * sizeof(int), stream);

    // h1 (fp16) + attention dots + degree count (merged)
    sAB_count<<<NN + CNT_BLOCKS, 256, 0, stream>>>(x, W1, as1i, ad1i, ei,
                                                   h1h, as1, ad1, cnt);
    // CSR build
    scan_a<<<SCAN_B, 1024, 0, stream>>>(cnt, offs, bsum);
    scan_c<<<SCAN_B, 1024, 0, stream>>>(offs, bsum, cur);
    c_scatter<<<(ETOT + 255) / 256, 256, 0, stream>>>(ei, cur, ssrc);
    // layer-1 gather (softmax + aggregate + BN + ELU)
    g1k<<<NN / 4, 256, 0, stream>>>((const uint2*)h1h, as1, ad1, offs, ssrc,
                                    b1, g1, be1, mu1, va1, (float4*)hpost);
    // layer 2
    sFG<<<NN / 8, 256, 0, stream>>>(hpost, W2, as2i, ad2i, h2h, as2, ad2);
    g2k<<<NN / 8, 256, 0, stream>>>((const unsigned short*)h2h, as2, ad2, offs,
                                    ssrc, b2, g2, be2, mu2, va2, out);
}

// Round 9
// 347.674 us; speedup vs baseline: 2.0331x; 1.2097x over previous
//
#include <hip/hip_runtime.h>
#include <hip/hip_fp16.h>
#include <math.h>

// Problem constants (from setup_inputs)
#define NN   50000          // nodes
#define EE   800000         // edges (without self loops)
#define ETOT 850000         // edges + self loops
#define INF_FEATS 22
#define D1   256            // HEADS*HID
#define NH   4
#define D2   32
#define BN_EPS 1e-5f
#define NEG_SLOPE 0.2f
#define SCAN_B 49
#define CNT_BLOCKS ((ETOT + 255) / 256)

typedef _Float16 f16x8 __attribute__((ext_vector_type(8)));
typedef float f32x4 __attribute__((ext_vector_type(4)));

__device__ __forceinline__ float wsum64(float v) {
#pragma unroll
    for (int m = 32; m > 0; m >>= 1) v += __shfl_xor(v, m);
    return v;
}

__device__ __forceinline__ float2 h2f(unsigned u) {
    __half2 h = *reinterpret_cast<__half2*>(&u);
    return __half22float2(h);
}

// ---------------------------------------------------------------------------
// sAB_count: blocks [0,NN): h1 = x@W1 (fp16) + fused attention dots.
//            blocks [NN, NN+CNT_BLOCKS): edge-parallel degree count.
__global__ __launch_bounds__(256) void sAB_count(
    const float* __restrict__ x, const float* __restrict__ W1,
    const float* __restrict__ atts, const float* __restrict__ attd,
    const int* __restrict__ ei, __half* __restrict__ h1h,
    float* __restrict__ as1, float* __restrict__ ad1, int* __restrict__ cnt) {
    if (blockIdx.x >= NN) {
        const int e = (blockIdx.x - NN) * 256 + threadIdx.x;
        if (e < ETOT) {
            int dst = (e < EE) ? ei[EE + e] : (e - EE);
            atomicAdd(&cnt[dst], 1);
        }
        return;
    }
    const int n = blockIdx.x, col = threadIdx.x;
    float a = 0.f;
#pragma unroll
    for (int k = 0; k < INF_FEATS; ++k)
        a = fmaf(x[n * INF_FEATS + k], W1[k * D1 + col], a);
    h1h[n * D1 + col] = __float2half(a);
    const int w = col >> 6, lane = col & 63;
    const float s = wsum64(a * atts[col]);
    const float d = wsum64(a * attd[col]);
    if (lane == 0) {
        as1[n * NH + w] = s;
        ad1[n * NH + w] = d;
    }
}

// ---------------------------------------------------------------------------
// scan_a: per-block local exclusive scan of cnt
__global__ __launch_bounds__(1024) void scan_a(const int* __restrict__ cnt,
                                               int* __restrict__ offs,
                                               int* __restrict__ bsum) {
    __shared__ int sh[1024];
    const int t = threadIdx.x, i = blockIdx.x * 1024 + t;
    const int v = (i < NN) ? cnt[i] : 0;
    sh[t] = v;
    __syncthreads();
    for (int off = 1; off < 1024; off <<= 1) {
        int u = (t >= off) ? sh[t - off] : 0;
        __syncthreads();
        sh[t] += u;
        __syncthreads();
    }
    if (i < NN) offs[i] = sh[t] - v;          // local exclusive
    if (t == 1023) bsum[blockIdx.x] = sh[1023];
}

// scan_c: add block base (computed in-block from bsum), emit offs + cur
__global__ __launch_bounds__(1024) void scan_c(int* __restrict__ offs,
                                               const int* __restrict__ bsum,
                                               int* __restrict__ cur) {
    __shared__ int sbase;
    if (threadIdx.x == 0) {
        int r = 0;
        for (int b = 0; b < blockIdx.x; ++b) r += bsum[b];
        sbase = r;
    }
    __syncthreads();
    const int i = blockIdx.x * 1024 + threadIdx.x;
    if (i < NN) {
        const int o = offs[i] + sbase;
        offs[i] = o;
        cur[i] = o;
    }
    if (i == 0) offs[NN] = ETOT;
}

__global__ void c_scatter(const int* __restrict__ ei, int* __restrict__ cur,
                          int* __restrict__ ssrc) {
    int e = blockIdx.x * blockDim.x + threadIdx.x;
    if (e >= ETOT) return;
    int src, dst;
    if (e < EE) { src = ei[e]; dst = ei[EE + e]; }
    else        { src = dst = e - EE; }
    int pos = atomicAdd(&cur[dst], 1);
    ssrc[pos] = src;
}

// ---------------------------------------------------------------------------
// g1k: layer-1 gather. One wave per node (4 nodes/block). Lane = 4 channels
// (uint2 = half4 load). Unroll x8 with predication for 8 gathers in flight.
// Epilogue: BN + ELU, store hpost as fp16 (consumed by MFMA sFGm).
__global__ __launch_bounds__(256) void g1k(
    const uint2* __restrict__ h1q, const float* __restrict__ as1,
    const float* __restrict__ ad1, const int* __restrict__ offs,
    const int* __restrict__ ssrc, const float* __restrict__ b1,
    const float* __restrict__ g1, const float* __restrict__ be1,
    const float* __restrict__ mu1, const float* __restrict__ va1,
    uint2* __restrict__ hposth) {
    const int wv = threadIdx.x >> 6, lane = threadIdx.x & 63;
    const int n = blockIdx.x * 4 + wv;       // grid exact: 12500*4
    const int off = offs[n];
    const int deg = offs[n + 1] - off;       // >= 1 (self loop)
    const int h = lane >> 4;                 // head = (lane*4)>>6
    const float adst = ad1[n * NH + h];
    float a0 = 0.f, a1 = 0.f, a2 = 0.f, a3 = 0.f, ssum = 0.f;
    for (int p = 0; p < deg; p += 8) {
        int sj[8];
        float al[8];
#pragma unroll
        for (int u = 0; u < 8; ++u)
            sj[u] = (p + u < deg) ? ssrc[off + p + u] : ssrc[off];
#pragma unroll
        for (int u = 0; u < 8; ++u) {
            float a = as1[sj[u] * NH + h] + adst;
            a = (a >= 0.f) ? a : NEG_SLOPE * a;
            al[u] = (p + u < deg) ? __expf(a) : 0.f;
        }
        uint2 hv[8];
#pragma unroll
        for (int u = 0; u < 8; ++u)
            hv[u] = h1q[(size_t)sj[u] * 64 + lane];
#pragma unroll
        for (int u = 0; u < 8; ++u) {
            ssum += al[u];
            const float2 f0 = h2f(hv[u].x), f1 = h2f(hv[u].y);
            a0 = fmaf(al[u], f0.x, a0);
            a1 = fmaf(al[u], f0.y, a1);
            a2 = fmaf(al[u], f1.x, a2);
            a3 = fmaf(al[u], f1.y, a3);
        }
    }
    const float inv = 1.f / (ssum + 1e-16f);
    const float4 bb = ((const float4*)b1)[lane];
    const float4 mm = ((const float4*)mu1)[lane];
    const float4 vv = ((const float4*)va1)[lane];
    const float4 gg = ((const float4*)g1)[lane];
    const float4 ee = ((const float4*)be1)[lane];
    float4 o;
    o.x = (a0 * inv + bb.x - mm.x) * rsqrtf(vv.x + BN_EPS) * gg.x + ee.x;
    o.y = (a1 * inv + bb.y - mm.y) * rsqrtf(vv.y + BN_EPS) * gg.y + ee.y;
    o.z = (a2 * inv + bb.z - mm.z) * rsqrtf(vv.z + BN_EPS) * gg.z + ee.z;
    o.w = (a3 * inv + bb.w - mm.w) * rsqrtf(vv.w + BN_EPS) * gg.w + ee.w;
    o.x = (o.x > 0.f) ? o.x : expm1f(o.x);
    o.y = (o.y > 0.f) ? o.y : expm1f(o.y);
    o.z = (o.z > 0.f) ? o.z : expm1f(o.z);
    o.w = (o.w > 0.f) ? o.w : expm1f(o.w);
    __half2 p01 = __floats2half2_rn(o.x, o.y);
    __half2 p23 = __floats2half2_rn(o.z, o.w);
    uint2 st;
    st.x = *reinterpret_cast<unsigned*>(&p01);
    st.y = *reinterpret_cast<unsigned*>(&p23);
    hposth[(size_t)n * 64 + lane] = st;
}

// ---------------------------------------------------------------------------
// sFGm: h2 = hpost(fp16) @ W2 via MFMA 16x16x32_f16, fused layer-2 dots.
// Block = 4 waves x 16 rows = 64 rows; each wave: 16x32 strip, K=256.
// A layout: row=lane&15, k=(lane>>4)*8+j (uint4 = 8 halves contiguous).
// B layout: col=lane&15, k=(lane>>4)*8+j (precomputed in regs from W2).
// C/D layout: col=lane&15, row=(lane>>4)*4+i  [m89-verified].
__global__ __launch_bounds__(256) void sFGm(
    const uint4* __restrict__ hq,          // hposth as uint4; row stride 32
    const float* __restrict__ W2,
    const float* __restrict__ atts, const float* __restrict__ attd,
    __half* __restrict__ h2h, float* __restrict__ as2, float* __restrict__ ad2) {
    const int w = threadIdx.x >> 6, l = threadIdx.x & 63;
    const int row0 = blockIdx.x * 64 + w * 16;
    const int lmod = l & 15, ldiv = l >> 4;
    // B fragments for both N-tiles (cols lmod, lmod+16), all 8 k-steps
    f16x8 b0[8], b1[8];
#pragma unroll
    for (int ks = 0; ks < 8; ++ks) {
#pragma unroll
        for (int j = 0; j < 8; ++j) {
            const int k = ks * 32 + ldiv * 8 + j;
            b0[ks][j] = (_Float16)W2[k * D2 + lmod];
            b1[ks][j] = (_Float16)W2[k * D2 + lmod + 16];
        }
    }
    f32x4 acc0 = {0.f, 0.f, 0.f, 0.f}, acc1 = {0.f, 0.f, 0.f, 0.f};
    const int arow = min(row0 + lmod, NN - 1);        // clamp tail rows
    const uint4* ap = hq + (size_t)arow * 32 + ldiv;  // +ks*4 per step
#pragma unroll
    for (int ks = 0; ks < 8; ++ks) {
        uint4 av = ap[ks * 4];
        f16x8 a = *reinterpret_cast<f16x8*>(&av);
        acc0 = __builtin_amdgcn_mfma_f32_16x16x32_f16(a, b0[ks], acc0, 0, 0, 0);
        acc1 = __builtin_amdgcn_mfma_f32_16x16x32_f16(a, b1[ks], acc1, 0, 0, 0);
    }
    const float a2s0 = atts[lmod], a2s1 = atts[lmod + 16];
    const float a2d0 = attd[lmod], a2d1 = attd[lmod + 16];
#pragma unroll
    for (int i = 0; i < 4; ++i) {
        const int r = row0 + ldiv * 4 + i;
        const bool ok = r < NN;
        if (ok) {
            h2h[(size_t)r * D2 + lmod]      = __float2half(acc0[i]);
            h2h[(size_t)r * D2 + lmod + 16] = __float2half(acc1[i]);
        }
        float s = acc0[i] * a2s0 + acc1[i] * a2s1;
        float d = acc0[i] * a2d0 + acc1[i] * a2d1;
#pragma unroll
        for (int m = 8; m > 0; m >>= 1) {   // reduce the 16 cols per row
            s += __shfl_xor(s, m);
            d += __shfl_xor(d, m);
        }
        if (ok && lmod == 0) { as2[r] = s; ad2[r] = d; }
    }
}

// ---------------------------------------------------------------------------
// g2k: layer-2 gather (fp16 h2, L2-resident). 8 nodes/block, unroll x8.
__global__ __launch_bounds__(256) void g2k(
    const unsigned short* __restrict__ h2u, const float* __restrict__ as2,
    const float* __restrict__ ad2, const int* __restrict__ offs,
    const int* __restrict__ ssrc, const float* __restrict__ b2,
    const float* __restrict__ g2, const float* __restrict__ be2,
    const float* __restrict__ mu2, const float* __restrict__ va2,
    float* __restrict__ out) {
    const int t = threadIdx.x;
    const int n = blockIdx.x * 8 + (t >> 5), c = t & 31;
    const int off = offs[n];
    const int deg = offs[n + 1] - off;
    const float adst = ad2[n];
    float ssum = 0.f, acc = 0.f;
    for (int p = 0; p < deg; p += 8) {
        int sj[8];
        float al[8];
#pragma unroll
        for (int u = 0; u < 8; ++u)
            sj[u] = (p + u < deg) ? ssrc[off + p + u] : ssrc[off];
#pragma unroll
        for (int u = 0; u < 8; ++u) {
            float a = as2[sj[u]] + adst;
            a = (a >= 0.f) ? a : NEG_SLOPE * a;
            al[u] = (p + u < deg) ? __expf(a) : 0.f;
        }
        unsigned short hv[8];
#pragma unroll
        for (int u = 0; u < 8; ++u)
            hv[u] = h2u[sj[u] * D2 + c];
#pragma unroll
        for (int u = 0; u < 8; ++u) {
            ssum += al[u];
            acc = fmaf(al[u], __half2float(*reinterpret_cast<__half*>(&hv[u])), acc);
        }
    }
    float v = acc / (ssum + 1e-16f) + b2[c];
    v = (v - mu2[c]) * rsqrtf(va2[c] + BN_EPS) * g2[c] + be2[c];
    v = (v > 0.f) ? v : expm1f(v);
    out[n * D2 + c] = v;
}

// ---------------------------------------------------------------------------
extern "C" void kernel_launch(void* const* d_in, const int* in_sizes, int n_in,
                              void* d_out, int out_size, void* d_ws, size_t ws_size,
                              hipStream_t stream) {
    (void)in_sizes; (void)n_in; (void)out_size; (void)ws_size;
    const float* x    = (const float*)d_in[0];
    const int*   ei   = (const int*)  d_in[1];
    const float* W1   = (const float*)d_in[2];
    const float* as1i = (const float*)d_in[3];
    const float* ad1i = (const float*)d_in[4];
    const float* b1   = (const float*)d_in[5];
    const float* W2   = (const float*)d_in[6];
    const float* as2i = (const float*)d_in[7];
    const float* ad2i = (const float*)d_in[8];
    const float* b2   = (const float*)d_in[9];
    const float* g1   = (const float*)d_in[10];
    const float* be1  = (const float*)d_in[11];
    const float* mu1  = (const float*)d_in[12];
    const float* va1  = (const float*)d_in[13];
    const float* g2   = (const float*)d_in[14];
    const float* be2  = (const float*)d_in[15];
    const float* mu2  = (const float*)d_in[16];
    const float* va2  = (const float*)d_in[17];
    float* out = (float*)d_out;

    // workspace layout (~61 MB, well under the 118.4 MB proven in Round 3)
    float* ws = (float*)d_ws;
    __half* hposth = (__half*)ws;                    // NN*256 halves (25.6 MB)
    float* as1  = ws + (size_t)NN * (D1 / 2);        // NN*4
    float* ad1  = as1 + (size_t)NN * NH;             // NN*4
    float* as2  = ad1 + (size_t)NN * NH;             // NN
    float* ad2  = as2 + NN;                          // NN
    __half* h1h = (__half*)(ad2 + NN);               // NN*256 halves (25.6 MB)
    __half* h2h = h1h + (size_t)NN * D1;             // NN*32 halves (3.2 MB)
    int* cnt   = (int*)(h2h + (size_t)NN * D2);      // NN
    int* offs  = cnt + NN;                           // NN+1
    int* cur   = offs + NN + 1;                      // NN
    int* ssrc  = cur + NN;                           // ETOT
    int* bsum  = ssrc + ETOT;                        // 49

    hipMemsetAsync(cnt, 0, NN * sizeof(int), stream);

    // h1 (fp16) + attention dots + degree count (merged)
    sAB_count<<<NN + CNT_BLOCKS, 256, 0, stream>>>(x, W1, as1i, ad1i, ei,
                                                   h1h, as1, ad1, cnt);
    // CSR build
    scan_a<<<SCAN_B, 1024, 0, stream>>>(cnt, offs, bsum);
    scan_c<<<SCAN_B, 1024, 0, stream>>>(offs, bsum, cur);
    c_scatter<<<(ETOT + 255) / 256, 256, 0, stream>>>(ei, cur, ssrc);
    // layer-1 gather (softmax + aggregate + BN + ELU, fp16 out)
    g1k<<<NN / 4, 256, 0, stream>>>((const uint2*)h1h, as1, ad1, offs, ssrc,
                                    b1, g1, be1, mu1, va1, (uint2*)hposth);
    // layer 2: MFMA linear + fused dots
    sFGm<<<(NN + 63) / 64, 256, 0, stream>>>((const uint4*)hposth, W2,
                                             as2i, ad2i, h2h, as2, ad2);
    g2k<<<NN / 8, 256, 0, stream>>>((const unsigned short*)h2h, as2, ad2, offs,
                                    ssrc, b2, g2, be2, mu2, va2, out);
}

// Round 10
// 315.869 us; speedup vs baseline: 2.2379x; 1.1007x over previous
//
#include <hip/hip_runtime.h>
#include <hip/hip_fp16.h>
#include <math.h>

// Problem constants (from setup_inputs)
#define NN   50000          // nodes
#define EE   800000         // edges (without self loops)
#define ETOT 850000         // edges + self loops
#define INF_FEATS 22
#define D1   256            // HEADS*HID
#define NH   4
#define D2   32
#define BN_EPS 1e-5f
#define NEG_SLOPE 0.2f
#define SCAN_B 49
#define AB_ROWS 8
#define AB_BLOCKS (NN / AB_ROWS)           // 6250 exact
#define CNT_BLOCKS ((ETOT + 255) / 256)

typedef _Float16 f16x8 __attribute__((ext_vector_type(8)));
typedef float f32x4 __attribute__((ext_vector_type(4)));

__device__ __forceinline__ float wsum64(float v) {
#pragma unroll
    for (int m = 32; m > 0; m >>= 1) v += __shfl_xor(v, m);
    return v;
}

__device__ __forceinline__ float2 h2f(unsigned u) {
    __half2 h = *reinterpret_cast<__half2*>(&u);
    return __half22float2(h);
}

// ---------------------------------------------------------------------------
// sAB_count: blocks [0,AB_BLOCKS): h1 = x@W1 (fp16, 8 rows/block, x in LDS)
//            + fused per-head attention dots.
//            blocks [AB_BLOCKS, ..): edge-parallel degree count + rank store.
__global__ __launch_bounds__(256) void sAB_count(
    const float* __restrict__ x, const float* __restrict__ W1,
    const float* __restrict__ atts, const float* __restrict__ attd,
    const int* __restrict__ ei, __half* __restrict__ h1h,
    float* __restrict__ as1, float* __restrict__ ad1,
    int* __restrict__ cnt, int* __restrict__ rank) {
    if (blockIdx.x >= AB_BLOCKS) {
        const int e = (blockIdx.x - AB_BLOCKS) * 256 + threadIdx.x;
        if (e < ETOT) {
            int dst = (e < EE) ? ei[EE + e] : (e - EE);
            rank[e] = atomicAdd(&cnt[dst], 1);   // position within dst bucket
        }
        return;
    }
    __shared__ float xs[AB_ROWS][INF_FEATS];
    const int t = threadIdx.x;
    const int n0 = blockIdx.x * AB_ROWS;
    for (int i = t; i < AB_ROWS * INF_FEATS; i += 256)
        xs[i / INF_FEATS][i % INF_FEATS] = x[n0 * INF_FEATS + i];
    __syncthreads();
    float acc[AB_ROWS];
#pragma unroll
    for (int r = 0; r < AB_ROWS; ++r) acc[r] = 0.f;
#pragma unroll
    for (int k = 0; k < INF_FEATS; ++k) {
        const float wv = W1[k * D1 + t];
#pragma unroll
        for (int r = 0; r < AB_ROWS; ++r) acc[r] = fmaf(xs[r][k], wv, acc[r]);
    }
    const float asv = atts[t], adv = attd[t];
    const int w = t >> 6, lane = t & 63;
#pragma unroll
    for (int r = 0; r < AB_ROWS; ++r) {
        const int n = n0 + r;
        h1h[(size_t)n * D1 + t] = __float2half(acc[r]);
        const float s = wsum64(acc[r] * asv);
        const float d = wsum64(acc[r] * adv);
        if (lane == 0) {
            as1[n * NH + w] = s;
            ad1[n * NH + w] = d;
        }
    }
}

// ---------------------------------------------------------------------------
// scan_a: per-block local exclusive scan of cnt
__global__ __launch_bounds__(1024) void scan_a(const int* __restrict__ cnt,
                                               int* __restrict__ offs,
                                               int* __restrict__ bsum) {
    __shared__ int sh[1024];
    const int t = threadIdx.x, i = blockIdx.x * 1024 + t;
    const int v = (i < NN) ? cnt[i] : 0;
    sh[t] = v;
    __syncthreads();
    for (int off = 1; off < 1024; off <<= 1) {
        int u = (t >= off) ? sh[t - off] : 0;
        __syncthreads();
        sh[t] += u;
        __syncthreads();
    }
    if (i < NN) offs[i] = sh[t] - v;          // local exclusive
    if (t == 1023) bsum[blockIdx.x] = sh[1023];
}

// scan_c: add block base (computed in-block from bsum)
__global__ __launch_bounds__(1024) void scan_c(int* __restrict__ offs,
                                               const int* __restrict__ bsum) {
    __shared__ int sbase;
    if (threadIdx.x == 0) {
        int r = 0;
        for (int b = 0; b < blockIdx.x; ++b) r += bsum[b];
        sbase = r;
    }
    __syncthreads();
    const int i = blockIdx.x * 1024 + threadIdx.x;
    if (i < NN) offs[i] += sbase;
    if (i == 0) offs[NN] = ETOT;
}

// c_scatter2: atomic-free scatter using precomputed ranks
__global__ void c_scatter2(const int* __restrict__ ei,
                           const int* __restrict__ offs,
                           const int* __restrict__ rank,
                           int* __restrict__ ssrc) {
    int e = blockIdx.x * blockDim.x + threadIdx.x;
    if (e >= ETOT) return;
    int src, dst;
    if (e < EE) { src = ei[e]; dst = ei[EE + e]; }
    else        { src = dst = e - EE; }
    ssrc[offs[dst] + rank[e]] = src;
}

// ---------------------------------------------------------------------------
// g1k: layer-1 gather. One wave per node (4 nodes/block). Lane = 4 channels
// (uint2 = half4 load). Unroll x8 with predication for 8 gathers in flight.
// Epilogue: BN + ELU, store hpost as fp16 (consumed by MFMA sFGm).
__global__ __launch_bounds__(256) void g1k(
    const uint2* __restrict__ h1q, const float* __restrict__ as1,
    const float* __restrict__ ad1, const int* __restrict__ offs,
    const int* __restrict__ ssrc, const float* __restrict__ b1,
    const float* __restrict__ g1, const float* __restrict__ be1,
    const float* __restrict__ mu1, const float* __restrict__ va1,
    uint2* __restrict__ hposth) {
    const int wv = threadIdx.x >> 6, lane = threadIdx.x & 63;
    const int n = blockIdx.x * 4 + wv;       // grid exact: 12500*4
    const int off = offs[n];
    const int deg = offs[n + 1] - off;       // >= 1 (self loop)
    const int h = lane >> 4;                 // head = (lane*4)>>6
    const float adst = ad1[n * NH + h];
    float a0 = 0.f, a1 = 0.f, a2 = 0.f, a3 = 0.f, ssum = 0.f;
    for (int p = 0; p < deg; p += 8) {
        int sj[8];
        float al[8];
#pragma unroll
        for (int u = 0; u < 8; ++u)
            sj[u] = (p + u < deg) ? ssrc[off + p + u] : ssrc[off];
#pragma unroll
        for (int u = 0; u < 8; ++u) {
            float a = as1[sj[u] * NH + h] + adst;
            a = (a >= 0.f) ? a : NEG_SLOPE * a;
            al[u] = (p + u < deg) ? __expf(a) : 0.f;
        }
        uint2 hv[8];
#pragma unroll
        for (int u = 0; u < 8; ++u)
            hv[u] = h1q[(size_t)sj[u] * 64 + lane];
#pragma unroll
        for (int u = 0; u < 8; ++u) {
            ssum += al[u];
            const float2 f0 = h2f(hv[u].x), f1 = h2f(hv[u].y);
            a0 = fmaf(al[u], f0.x, a0);
            a1 = fmaf(al[u], f0.y, a1);
            a2 = fmaf(al[u], f1.x, a2);
            a3 = fmaf(al[u], f1.y, a3);
        }
    }
    const float inv = 1.f / (ssum + 1e-16f);
    const float4 bb = ((const float4*)b1)[lane];
    const float4 mm = ((const float4*)mu1)[lane];
    const float4 vv = ((const float4*)va1)[lane];
    const float4 gg = ((const float4*)g1)[lane];
    const float4 ee = ((const float4*)be1)[lane];
    float4 o;
    o.x = (a0 * inv + bb.x - mm.x) * rsqrtf(vv.x + BN_EPS) * gg.x + ee.x;
    o.y = (a1 * inv + bb.y - mm.y) * rsqrtf(vv.y + BN_EPS) * gg.y + ee.y;
    o.z = (a2 * inv + bb.z - mm.z) * rsqrtf(vv.z + BN_EPS) * gg.z + ee.z;
    o.w = (a3 * inv + bb.w - mm.w) * rsqrtf(vv.w + BN_EPS) * gg.w + ee.w;
    o.x = (o.x > 0.f) ? o.x : expm1f(o.x);
    o.y = (o.y > 0.f) ? o.y : expm1f(o.y);
    o.z = (o.z > 0.f) ? o.z : expm1f(o.z);
    o.w = (o.w > 0.f) ? o.w : expm1f(o.w);
    __half2 p01 = __floats2half2_rn(o.x, o.y);
    __half2 p23 = __floats2half2_rn(o.z, o.w);
    uint2 st;
    st.x = *reinterpret_cast<unsigned*>(&p01);
    st.y = *reinterpret_cast<unsigned*>(&p23);
    hposth[(size_t)n * 64 + lane] = st;
}

// ---------------------------------------------------------------------------
// sFGm: h2 = hpost(fp16) @ W2 via MFMA 16x16x32_f16, fused layer-2 dots.
// Block = 4 waves x 16 rows = 64 rows; each wave: 16x32 strip, K=256.
// A layout: row=lane&15, k=(lane>>4)*8+j. B layout: col=lane&15, same k.
// C/D layout: col=lane&15, row=(lane>>4)*4+i  [m89-verified].
__global__ __launch_bounds__(256) void sFGm(
    const uint4* __restrict__ hq,          // hposth as uint4; row stride 32
    const float* __restrict__ W2,
    const float* __restrict__ atts, const float* __restrict__ attd,
    __half* __restrict__ h2h, float* __restrict__ as2, float* __restrict__ ad2) {
    const int w = threadIdx.x >> 6, l = threadIdx.x & 63;
    const int row0 = blockIdx.x * 64 + w * 16;
    const int lmod = l & 15, ldiv = l >> 4;
    f16x8 b0[8], b1[8];
#pragma unroll
    for (int ks = 0; ks < 8; ++ks) {
#pragma unroll
        for (int j = 0; j < 8; ++j) {
            const int k = ks * 32 + ldiv * 8 + j;
            b0[ks][j] = (_Float16)W2[k * D2 + lmod];
            b1[ks][j] = (_Float16)W2[k * D2 + lmod + 16];
        }
    }
    f32x4 acc0 = {0.f, 0.f, 0.f, 0.f}, acc1 = {0.f, 0.f, 0.f, 0.f};
    const int arow = min(row0 + lmod, NN - 1);        // clamp tail rows
    const uint4* ap = hq + (size_t)arow * 32 + ldiv;  // +ks*4 per step
#pragma unroll
    for (int ks = 0; ks < 8; ++ks) {
        uint4 av = ap[ks * 4];
        f16x8 a = *reinterpret_cast<f16x8*>(&av);
        acc0 = __builtin_amdgcn_mfma_f32_16x16x32_f16(a, b0[ks], acc0, 0, 0, 0);
        acc1 = __builtin_amdgcn_mfma_f32_16x16x32_f16(a, b1[ks], acc1, 0, 0, 0);
    }
    const float a2s0 = atts[lmod], a2s1 = atts[lmod + 16];
    const float a2d0 = attd[lmod], a2d1 = attd[lmod + 16];
#pragma unroll
    for (int i = 0; i < 4; ++i) {
        const int r = row0 + ldiv * 4 + i;
        const bool ok = r < NN;
        if (ok) {
            h2h[(size_t)r * D2 + lmod]      = __float2half(acc0[i]);
            h2h[(size_t)r * D2 + lmod + 16] = __float2half(acc1[i]);
        }
        float s = acc0[i] * a2s0 + acc1[i] * a2s1;
        float d = acc0[i] * a2d0 + acc1[i] * a2d1;
#pragma unroll
        for (int m = 8; m > 0; m >>= 1) {
            s += __shfl_xor(s, m);
            d += __shfl_xor(d, m);
        }
        if (ok && lmod == 0) { as2[r] = s; ad2[r] = d; }
    }
}

// ---------------------------------------------------------------------------
// g2k: layer-2 gather (fp16 h2, L2-resident). 8 nodes/block, unroll x8.
__global__ __launch_bounds__(256) void g2k(
    const unsigned short* __restrict__ h2u, const float* __restrict__ as2,
    const float* __restrict__ ad2, const int* __restrict__ offs,
    const int* __restrict__ ssrc, const float* __restrict__ b2,
    const float* __restrict__ g2, const float* __restrict__ be2,
    const float* __restrict__ mu2, const float* __restrict__ va2,
    float* __restrict__ out) {
    const int t = threadIdx.x;
    const int n = blockIdx.x * 8 + (t >> 5), c = t & 31;
    const int off = offs[n];
    const int deg = offs[n + 1] - off;
    const float adst = ad2[n];
    float ssum = 0.f, acc = 0.f;
    for (int p = 0; p < deg; p += 8) {
        int sj[8];
        float al[8];
#pragma unroll
        for (int u = 0; u < 8; ++u)
            sj[u] = (p + u < deg) ? ssrc[off + p + u] : ssrc[off];
#pragma unroll
        for (int u = 0; u < 8; ++u) {
            float a = as2[sj[u]] + adst;
            a = (a >= 0.f) ? a : NEG_SLOPE * a;
            al[u] = (p + u < deg) ? __expf(a) : 0.f;
        }
        unsigned short hv[8];
#pragma unroll
        for (int u = 0; u < 8; ++u)
            hv[u] = h2u[sj[u] * D2 + c];
#pragma unroll
        for (int u = 0; u < 8; ++u) {
            ssum += al[u];
            acc = fmaf(al[u], __half2float(*reinterpret_cast<__half*>(&hv[u])), acc);
        }
    }
    float v = acc / (ssum + 1e-16f) + b2[c];
    v = (v - mu2[c]) * rsqrtf(va2[c] + BN_EPS) * g2[c] + be2[c];
    v = (v > 0.f) ? v : expm1f(v);
    out[n * D2 + c] = v;
}

// ---------------------------------------------------------------------------
extern "C" void kernel_launch(void* const* d_in, const int* in_sizes, int n_in,
                              void* d_out, int out_size, void* d_ws, size_t ws_size,
                              hipStream_t stream) {
    (void)in_sizes; (void)n_in; (void)out_size; (void)ws_size;
    const float* x    = (const float*)d_in[0];
    const int*   ei   = (const int*)  d_in[1];
    const float* W1   = (const float*)d_in[2];
    const float* as1i = (const float*)d_in[3];
    const float* ad1i = (const float*)d_in[4];
    const float* b1   = (const float*)d_in[5];
    const float* W2   = (const float*)d_in[6];
    const float* as2i = (const float*)d_in[7];
    const float* ad2i = (const float*)d_in[8];
    const float* b2   = (const float*)d_in[9];
    const float* g1   = (const float*)d_in[10];
    const float* be1  = (const float*)d_in[11];
    const float* mu1  = (const float*)d_in[12];
    const float* va1  = (const float*)d_in[13];
    const float* g2   = (const float*)d_in[14];
    const float* be2  = (const float*)d_in[15];
    const float* mu2  = (const float*)d_in[16];
    const float* va2  = (const float*)d_in[17];
    float* out = (float*)d_out;

    // workspace layout (~65 MB, well under the 118.4 MB proven in Round 3)
    float* ws = (float*)d_ws;
    __half* hposth = (__half*)ws;                    // NN*256 halves (25.6 MB)
    float* as1  = ws + (size_t)NN * (D1 / 2);        // NN*4
    float* ad1  = as1 + (size_t)NN * NH;             // NN*4
    float* as2  = ad1 + (size_t)NN * NH;             // NN
    float* ad2  = as2 + NN;                          // NN
    __half* h1h = (__half*)(ad2 + NN);               // NN*256 halves (25.6 MB)
    __half* h2h = h1h + (size_t)NN * D1;             // NN*32 halves (3.2 MB)
    int* cnt   = (int*)(h2h + (size_t)NN * D2);      // NN
    int* offs  = cnt + NN;                           // NN+1
    int* rank  = offs + NN + 1;                      // ETOT
    int* ssrc  = rank + ETOT;                        // ETOT
    int* bsum  = ssrc + ETOT;                        // 49

    hipMemsetAsync(cnt, 0, NN * sizeof(int), stream);

    // h1 (fp16, 8 rows/block) + attention dots + degree count w/ rank (merged)
    sAB_count<<<AB_BLOCKS + CNT_BLOCKS, 256, 0, stream>>>(
        x, W1, as1i, ad1i, ei, h1h, as1, ad1, cnt, rank);
    // CSR build (atomic-free scatter)
    scan_a<<<SCAN_B, 1024, 0, stream>>>(cnt, offs, bsum);
    scan_c<<<SCAN_B, 1024, 0, stream>>>(offs, bsum);
    c_scatter2<<<(ETOT + 255) / 256, 256, 0, stream>>>(ei, offs, rank, ssrc);
    // layer-1 gather (softmax + aggregate + BN + ELU, fp16 out)
    g1k<<<NN / 4, 256, 0, stream>>>((const uint2*)h1h, as1, ad1, offs, ssrc,
                                    b1, g1, be1, mu1, va1, (uint2*)hposth);
    // layer 2: MFMA linear + fused dots
    sFGm<<<(NN + 63) / 64, 256, 0, stream>>>((const uint4*)hposth, W2,
                                             as2i, ad2i, h2h, as2, ad2);
    g2k<<<NN / 8, 256, 0, stream>>>((const unsigned short*)h2h, as2, ad2, offs,
                                    ssrc, b2, g2, be2, mu2, va2, out);
}

// Round 11
// 292.539 us; speedup vs baseline: 2.4163x; 1.0798x over previous
//
#include <hip/hip_runtime.h>
#include <hip/hip_fp16.h>
#include <math.h>

// Problem constants (from setup_inputs)
#define NN   50000          // nodes
#define EE   800000         // edges (without self loops)
#define ETOT 850000         // edges + self loops
#define INF_FEATS 22
#define D1   256            // HEADS*HID
#define NH   4
#define D2   32
#define BN_EPS 1e-5f
#define NEG_SLOPE 0.2f
#define SCAN_B 49
#define AB_ROWS 8
#define AB_BLOCKS (NN / AB_ROWS)           // 6250 exact
#define CNT_BLOCKS ((ETOT + 255) / 256)

typedef _Float16 f16x8 __attribute__((ext_vector_type(8)));
typedef float f32x4 __attribute__((ext_vector_type(4)));

__device__ __forceinline__ float2 h2f(unsigned u) {
    __half2 h = *reinterpret_cast<__half2*>(&u);
    return __half22float2(h);
}

// ---------------------------------------------------------------------------
// prep: WA[k,h] = sum_c W1[k, h*64+c] * att[h,c]  (22x4, for src and dst)
__global__ __launch_bounds__(128) void prep(const float* __restrict__ W1,
                                            const float* __restrict__ atts,
                                            const float* __restrict__ attd,
                                            float* __restrict__ WAs,
                                            float* __restrict__ WAd) {
    const int t = threadIdx.x;
    if (t >= INF_FEATS * NH) return;      // 88 pairs
    const int k = t >> 2, h = t & 3;
    float s = 0.f, d = 0.f;
    for (int c = 0; c < 64; ++c) {
        const float w = W1[k * D1 + h * 64 + c];
        s = fmaf(w, atts[h * 64 + c], s);
        d = fmaf(w, attd[h * 64 + c], d);
    }
    WAs[k * NH + h] = s;
    WAd[k * NH + h] = d;
}

// ---------------------------------------------------------------------------
// sAB_count: blocks [0,AB_BLOCKS): h1 = x@W1 (fp16, 8 rows/block, x in LDS)
//            + as1/ad1 via the precomputed 22x4 WA matrices (no shuffles).
//            blocks [AB_BLOCKS, ..): edge-parallel degree count + rank store.
__global__ __launch_bounds__(256) void sAB_count(
    const float* __restrict__ x, const float* __restrict__ W1,
    const float* __restrict__ WAs, const float* __restrict__ WAd,
    const int* __restrict__ ei, __half* __restrict__ h1h,
    float* __restrict__ as1, float* __restrict__ ad1,
    int* __restrict__ cnt, int* __restrict__ rank) {
    if (blockIdx.x >= AB_BLOCKS) {
        const int e = (blockIdx.x - AB_BLOCKS) * 256 + threadIdx.x;
        if (e < ETOT) {
            int dst = (e < EE) ? ei[EE + e] : (e - EE);
            rank[e] = atomicAdd(&cnt[dst], 1);   // position within dst bucket
        }
        return;
    }
    __shared__ float xs[AB_ROWS][INF_FEATS];
    const int t = threadIdx.x;
    const int n0 = blockIdx.x * AB_ROWS;
    for (int i = t; i < AB_ROWS * INF_FEATS; i += 256)
        xs[i / INF_FEATS][i % INF_FEATS] = x[n0 * INF_FEATS + i];
    __syncthreads();
    float acc[AB_ROWS];
#pragma unroll
    for (int r = 0; r < AB_ROWS; ++r) acc[r] = 0.f;
#pragma unroll
    for (int k = 0; k < INF_FEATS; ++k) {
        const float wv = W1[k * D1 + t];
#pragma unroll
        for (int r = 0; r < AB_ROWS; ++r) acc[r] = fmaf(xs[r][k], wv, acc[r]);
    }
#pragma unroll
    for (int r = 0; r < AB_ROWS; ++r)
        h1h[(size_t)(n0 + r) * D1 + t] = __float2half(acc[r]);
    // attention dots: 64 threads, each one (row, head, src/dst) triple
    if (t < AB_ROWS * NH * 2) {
        const int r = t >> 3, idx = t & 7, h = idx >> 1;
        const float* WA = (idx & 1) ? WAd : WAs;
        float a = 0.f;
#pragma unroll
        for (int k = 0; k < INF_FEATS; ++k)
            a = fmaf(xs[r][k], WA[k * NH + h], a);
        ((idx & 1) ? ad1 : as1)[(n0 + r) * NH + h] = a;
    }
}

// ---------------------------------------------------------------------------
// scan_a: per-block local exclusive scan of cnt
__global__ __launch_bounds__(1024) void scan_a(const int* __restrict__ cnt,
                                               int* __restrict__ offs,
                                               int* __restrict__ bsum) {
    __shared__ int sh[1024];
    const int t = threadIdx.x, i = blockIdx.x * 1024 + t;
    const int v = (i < NN) ? cnt[i] : 0;
    sh[t] = v;
    __syncthreads();
    for (int off = 1; off < 1024; off <<= 1) {
        int u = (t >= off) ? sh[t - off] : 0;
        __syncthreads();
        sh[t] += u;
        __syncthreads();
    }
    if (i < NN) offs[i] = sh[t] - v;          // local exclusive
    if (t == 1023) bsum[blockIdx.x] = sh[1023];
}

// scan_c: add block base (computed in-block from bsum)
__global__ __launch_bounds__(1024) void scan_c(int* __restrict__ offs,
                                               const int* __restrict__ bsum) {
    __shared__ int sbase;
    if (threadIdx.x == 0) {
        int r = 0;
        for (int b = 0; b < blockIdx.x; ++b) r += bsum[b];
        sbase = r;
    }
    __syncthreads();
    const int i = blockIdx.x * 1024 + threadIdx.x;
    if (i < NN) offs[i] += sbase;
    if (i == 0) offs[NN] = ETOT;
}

// c_scatter2: atomic-free scatter using precomputed ranks
__global__ void c_scatter2(const int* __restrict__ ei,
                           const int* __restrict__ offs,
                           const int* __restrict__ rank,
                           int* __restrict__ ssrc) {
    int e = blockIdx.x * blockDim.x + threadIdx.x;
    if (e >= ETOT) return;
    int src, dst;
    if (e < EE) { src = ei[e]; dst = ei[EE + e]; }
    else        { src = dst = e - EE; }
    ssrc[offs[dst] + rank[e]] = src;
}

// ---------------------------------------------------------------------------
// g1k: layer-1 gather. One wave per node (4 nodes/block). Lane = 4 channels
// (uint2 = half4 load). Unroll x8 with predication for 8 gathers in flight.
// Epilogue: BN + ELU, store hpost as fp16 (consumed by MFMA sFGm).
__global__ __launch_bounds__(256) void g1k(
    const uint2* __restrict__ h1q, const float* __restrict__ as1,
    const float* __restrict__ ad1, const int* __restrict__ offs,
    const int* __restrict__ ssrc, const float* __restrict__ b1,
    const float* __restrict__ g1, const float* __restrict__ be1,
    const float* __restrict__ mu1, const float* __restrict__ va1,
    uint2* __restrict__ hposth) {
    const int wv = threadIdx.x >> 6, lane = threadIdx.x & 63;
    const int n = blockIdx.x * 4 + wv;       // grid exact: 12500*4
    const int off = offs[n];
    const int deg = offs[n + 1] - off;       // >= 1 (self loop)
    const int h = lane >> 4;                 // head = (lane*4)>>6
    const float adst = ad1[n * NH + h];
    float a0 = 0.f, a1 = 0.f, a2 = 0.f, a3 = 0.f, ssum = 0.f;
    for (int p = 0; p < deg; p += 8) {
        int sj[8];
        float al[8];
#pragma unroll
        for (int u = 0; u < 8; ++u)
            sj[u] = (p + u < deg) ? ssrc[off + p + u] : ssrc[off];
#pragma unroll
        for (int u = 0; u < 8; ++u) {
            float a = as1[sj[u] * NH + h] + adst;
            a = (a >= 0.f) ? a : NEG_SLOPE * a;
            al[u] = (p + u < deg) ? __expf(a) : 0.f;
        }
        uint2 hv[8];
#pragma unroll
        for (int u = 0; u < 8; ++u)
            hv[u] = h1q[(size_t)sj[u] * 64 + lane];
#pragma unroll
        for (int u = 0; u < 8; ++u) {
            ssum += al[u];
            const float2 f0 = h2f(hv[u].x), f1 = h2f(hv[u].y);
            a0 = fmaf(al[u], f0.x, a0);
            a1 = fmaf(al[u], f0.y, a1);
            a2 = fmaf(al[u], f1.x, a2);
            a3 = fmaf(al[u], f1.y, a3);
        }
    }
    const float inv = 1.f / (ssum + 1e-16f);
    const float4 bb = ((const float4*)b1)[lane];
    const float4 mm = ((const float4*)mu1)[lane];
    const float4 vv = ((const float4*)va1)[lane];
    const float4 gg = ((const float4*)g1)[lane];
    const float4 ee = ((const float4*)be1)[lane];
    float4 o;
    o.x = (a0 * inv + bb.x - mm.x) * rsqrtf(vv.x + BN_EPS) * gg.x + ee.x;
    o.y = (a1 * inv + bb.y - mm.y) * rsqrtf(vv.y + BN_EPS) * gg.y + ee.y;
    o.z = (a2 * inv + bb.z - mm.z) * rsqrtf(vv.z + BN_EPS) * gg.z + ee.z;
    o.w = (a3 * inv + bb.w - mm.w) * rsqrtf(vv.w + BN_EPS) * gg.w + ee.w;
    o.x = (o.x > 0.f) ? o.x : expm1f(o.x);
    o.y = (o.y > 0.f) ? o.y : expm1f(o.y);
    o.z = (o.z > 0.f) ? o.z : expm1f(o.z);
    o.w = (o.w > 0.f) ? o.w : expm1f(o.w);
    __half2 p01 = __floats2half2_rn(o.x, o.y);
    __half2 p23 = __floats2half2_rn(o.z, o.w);
    uint2 st;
    st.x = *reinterpret_cast<unsigned*>(&p01);
    st.y = *reinterpret_cast<unsigned*>(&p23);
    hposth[(size_t)n * 64 + lane] = st;
}

// ---------------------------------------------------------------------------
// sFGm: h2 = hpost(fp16) @ W2 via MFMA 16x16x32_f16, fused layer-2 dots.
// Block = 4 waves x 16 rows = 64 rows; each wave: 16x32 strip, K=256.
// A layout: row=lane&15, k=(lane>>4)*8+j. B layout: col=lane&15, same k.
// C/D layout: col=lane&15, row=(lane>>4)*4+i  [m89-verified].
__global__ __launch_bounds__(256) void sFGm(
    const uint4* __restrict__ hq,          // hposth as uint4; row stride 32
    const float* __restrict__ W2,
    const float* __restrict__ atts, const float* __restrict__ attd,
    __half* __restrict__ h2h, float* __restrict__ as2, float* __restrict__ ad2) {
    const int w = threadIdx.x >> 6, l = threadIdx.x & 63;
    const int row0 = blockIdx.x * 64 + w * 16;
    const int lmod = l & 15, ldiv = l >> 4;
    f16x8 b0[8], b1[8];
#pragma unroll
    for (int ks = 0; ks < 8; ++ks) {
#pragma unroll
        for (int j = 0; j < 8; ++j) {
            const int k = ks * 32 + ldiv * 8 + j;
            b0[ks][j] = (_Float16)W2[k * D2 + lmod];
            b1[ks][j] = (_Float16)W2[k * D2 + lmod + 16];
        }
    }
    f32x4 acc0 = {0.f, 0.f, 0.f, 0.f}, acc1 = {0.f, 0.f, 0.f, 0.f};
    const int arow = min(row0 + lmod, NN - 1);        // clamp tail rows
    const uint4* ap = hq + (size_t)arow * 32 + ldiv;  // +ks*4 per step
#pragma unroll
    for (int ks = 0; ks < 8; ++ks) {
        uint4 av = ap[ks * 4];
        f16x8 a = *reinterpret_cast<f16x8*>(&av);
        acc0 = __builtin_amdgcn_mfma_f32_16x16x32_f16(a, b0[ks], acc0, 0, 0, 0);
        acc1 = __builtin_amdgcn_mfma_f32_16x16x32_f16(a, b1[ks], acc1, 0, 0, 0);
    }
    const float a2s0 = atts[lmod], a2s1 = atts[lmod + 16];
    const float a2d0 = attd[lmod], a2d1 = attd[lmod + 16];
#pragma unroll
    for (int i = 0; i < 4; ++i) {
        const int r = row0 + ldiv * 4 + i;
        const bool ok = r < NN;
        if (ok) {
            h2h[(size_t)r * D2 + lmod]      = __float2half(acc0[i]);
            h2h[(size_t)r * D2 + lmod + 16] = __float2half(acc1[i]);
        }
        float s = acc0[i] * a2s0 + acc1[i] * a2s1;
        float d = acc0[i] * a2d0 + acc1[i] * a2d1;
#pragma unroll
        for (int m = 8; m > 0; m >>= 1) {
            s += __shfl_xor(s, m);
            d += __shfl_xor(d, m);
        }
        if (ok && lmod == 0) { as2[r] = s; ad2[r] = d; }
    }
}

// ---------------------------------------------------------------------------
// g2k: layer-2 gather (fp16 h2, L2-resident). 8 nodes/block, unroll x8.
__global__ __launch_bounds__(256) void g2k(
    const unsigned short* __restrict__ h2u, const float* __restrict__ as2,
    const float* __restrict__ ad2, const int* __restrict__ offs,
    const int* __restrict__ ssrc, const float* __restrict__ b2,
    const float* __restrict__ g2, const float* __restrict__ be2,
    const float* __restrict__ mu2, const float* __restrict__ va2,
    float* __restrict__ out) {
    const int t = threadIdx.x;
    const int n = blockIdx.x * 8 + (t >> 5), c = t & 31;
    const int off = offs[n];
    const int deg = offs[n + 1] - off;
    const float adst = ad2[n];
    float ssum = 0.f, acc = 0.f;
    for (int p = 0; p < deg; p += 8) {
        int sj[8];
        float al[8];
#pragma unroll
        for (int u = 0; u < 8; ++u)
            sj[u] = (p + u < deg) ? ssrc[off + p + u] : ssrc[off];
#pragma unroll
        for (int u = 0; u < 8; ++u) {
            float a = as2[sj[u]] + adst;
            a = (a >= 0.f) ? a : NEG_SLOPE * a;
            al[u] = (p + u < deg) ? __expf(a) : 0.f;
        }
        unsigned short hv[8];
#pragma unroll
        for (int u = 0; u < 8; ++u)
            hv[u] = h2u[sj[u] * D2 + c];
#pragma unroll
        for (int u = 0; u < 8; ++u) {
            ssum += al[u];
            acc = fmaf(al[u], __half2float(*reinterpret_cast<__half*>(&hv[u])), acc);
        }
    }
    float v = acc / (ssum + 1e-16f) + b2[c];
    v = (v - mu2[c]) * rsqrtf(va2[c] + BN_EPS) * g2[c] + be2[c];
    v = (v > 0.f) ? v : expm1f(v);
    out[n * D2 + c] = v;
}

// ---------------------------------------------------------------------------
extern "C" void kernel_launch(void* const* d_in, const int* in_sizes, int n_in,
                              void* d_out, int out_size, void* d_ws, size_t ws_size,
                              hipStream_t stream) {
    (void)in_sizes; (void)n_in; (void)out_size; (void)ws_size;
    const float* x    = (const float*)d_in[0];
    const int*   ei   = (const int*)  d_in[1];
    const float* W1   = (const float*)d_in[2];
    const float* as1i = (const float*)d_in[3];
    const float* ad1i = (const float*)d_in[4];
    const float* b1   = (const float*)d_in[5];
    const float* W2   = (const float*)d_in[6];
    const float* as2i = (const float*)d_in[7];
    const float* ad2i = (const float*)d_in[8];
    const float* b2   = (const float*)d_in[9];
    const float* g1   = (const float*)d_in[10];
    const float* be1  = (const float*)d_in[11];
    const float* mu1  = (const float*)d_in[12];
    const float* va1  = (const float*)d_in[13];
    const float* g2   = (const float*)d_in[14];
    const float* be2  = (const float*)d_in[15];
    const float* mu2  = (const float*)d_in[16];
    const float* va2  = (const float*)d_in[17];
    float* out = (float*)d_out;

    // workspace layout (~65 MB, well under the 118.4 MB proven in Round 3)
    float* ws = (float*)d_ws;
    __half* hposth = (__half*)ws;                    // NN*256 halves (25.6 MB)
    float* as1  = ws + (size_t)NN * (D1 / 2);        // NN*4
    float* ad1  = as1 + (size_t)NN * NH;             // NN*4
    float* as2  = ad1 + (size_t)NN * NH;             // NN
    float* ad2  = as2 + NN;                          // NN
    __half* h1h = (__half*)(ad2 + NN);               // NN*256 halves (25.6 MB)
    __half* h2h = h1h + (size_t)NN * D1;             // NN*32 halves (3.2 MB)
    int* cnt   = (int*)(h2h + (size_t)NN * D2);      // NN
    int* offs  = cnt + NN;                           // NN+1
    int* rank  = offs + NN + 1;                      // ETOT
    int* ssrc  = rank + ETOT;                        // ETOT
    int* bsum  = ssrc + ETOT;                        // 49
    float* WAs = (float*)(bsum + SCAN_B);            // 22*4
    float* WAd = WAs + INF_FEATS * NH;               // 22*4

    hipMemsetAsync(cnt, 0, NN * sizeof(int), stream);

    // WA matrices (tiny)
    prep<<<1, 128, 0, stream>>>(W1, as1i, ad1i, WAs, WAd);
    // h1 (fp16, 8 rows/block) + attention dots via WA + degree count w/ rank
    sAB_count<<<AB_BLOCKS + CNT_BLOCKS, 256, 0, stream>>>(
        x, W1, WAs, WAd, ei, h1h, as1, ad1, cnt, rank);
    // CSR build (atomic-free scatter)
    scan_a<<<SCAN_B, 1024, 0, stream>>>(cnt, offs, bsum);
    scan_c<<<SCAN_B, 1024, 0, stream>>>(offs, bsum);
    c_scatter2<<<(ETOT + 255) / 256, 256, 0, stream>>>(ei, offs, rank, ssrc);
    // layer-1 gather (softmax + aggregate + BN + ELU, fp16 out)
    g1k<<<NN / 4, 256, 0, stream>>>((const uint2*)h1h, as1, ad1, offs, ssrc,
                                    b1, g1, be1, mu1, va1, (uint2*)hposth);
    // layer 2: MFMA linear + fused dots
    sFGm<<<(NN + 63) / 64, 256, 0, stream>>>((const uint4*)hposth, W2,
                                             as2i, ad2i, h2h, as2, ad2);
    g2k<<<NN / 8, 256, 0, stream>>>((const unsigned short*)h2h, as2, ad2, offs,
                                    ssrc, b2, g2, be2, mu2, va2, out);
}